// Round 1
// baseline (687.857 us; speedup 1.0000x reference)
//
#include <hip/hip_runtime.h>
#include <stdint.h>

constexpr int N_ATOMS = 64;
constexpr int NC2 = N_ATOMS * (N_ATOMS - 1) / 2;  // 2016
constexpr int BATCH = 32768;
constexpr int ROWS_PER_BLOCK = 8;
constexpr int NBLOCKS = BATCH / ROWS_PER_BLOCK;   // 4096
constexpr int BUF_FLOATS = 2048;                  // 8 KB per buffer (2016 data + zero slot + pad)

// Async global->LDS copy of one 16-byte chunk (wave-lane-linear destinations).
__device__ __forceinline__ void stage_chunk16(const float* g, float* l) {
    __builtin_amdgcn_global_load_lds(
        (const __attribute__((address_space(1))) void*)g,
        (__attribute__((address_space(3))) void*)l, 16, 0, 0);
}

__global__ __launch_bounds__(256) void triangle_kernel(
    const float* __restrict__ in, float* __restrict__ out) {
    __shared__ __align__(16) float sm[2][BUF_FLOATS];

    const int t = threadIdx.x;

    // Zero the "diagonal source" slot of both buffers once. Staging only ever
    // writes floats [0, 2016), so these survive all 8 rows.
    if (t == 0) {
        sm[0][2016] = 0.0f;
        sm[1][2016] = 0.0f;
    }

    // --- Hoisted per-thread gather offsets (depend only on threadIdx) ---
    // Thread t emits output float4s e4 = it*256+t; element e -> source index:
    //   j<i : i(i-1)/2 + j   (contiguous lower triangle)
    //   j>i : j(j-1)/2 + i   (mirrored upper triangle)
    //   j==i: 2016           (the zero slot)
    int srcB[16];  // byte offsets into one LDS buffer
#pragma unroll
    for (int it = 0; it < 4; ++it) {
        const int e4 = it * 256 + t;
        const int e = e4 * 4;
        const int i = e >> 6;
        const int j0 = e & 63;
        const int bl = i * (i - 1) / 2;
#pragma unroll
        for (int k = 0; k < 4; ++k) {
            const int j = j0 + k;
            int s;
            if (j < i)      s = bl + j;
            else if (j > i) s = j * (j - 1) / 2 + i;
            else            s = 2016;
            srcB[it * 4 + k] = s * 4;
        }
    }

    const int b0 = blockIdx.x * ROWS_PER_BLOCK;
    const float* rowPtr = in + (size_t)b0 * NC2;

    // --- Prologue: stage row 0 into buffer 0, full drain once ---
    stage_chunk16(rowPtr + 4 * t,         &sm[0][0] + 4 * t);
    stage_chunk16(rowPtr + 4 * (248 + t), &sm[0][0] + 4 * (248 + t));  // chunks 248..503 (8 chunks double-staged, benign)
    __syncthreads();

#pragma unroll
    for (int k = 0; k < ROWS_PER_BLOCK; ++k) {
        // Issue 1-deep prefetch of the next row into the other buffer.
        if (k + 1 < ROWS_PER_BLOCK) {
            const float* nxt = rowPtr + NC2;
            float* dst = &sm[(k + 1) & 1][0];
            stage_chunk16(nxt + 4 * t,         dst + 4 * t);
            stage_chunk16(nxt + 4 * (248 + t), dst + 4 * (248 + t));
        }

        if (k > 0) {
            // Counted wait: allow {4 stores of row k-1} + {2 prefetch loads of
            // row k+1} to stay in flight; forces row k's stage loads retired.
            if (k + 1 < ROWS_PER_BLOCK) {
                asm volatile("s_waitcnt vmcnt(6)" ::: "memory");
            } else {
                asm volatile("s_waitcnt vmcnt(4)" ::: "memory");  // last row: no prefetch outstanding
            }
            __builtin_amdgcn_s_barrier();
            __builtin_amdgcn_sched_barrier(0);
        }
        // (k == 0: buffer 0 readiness was established by the prologue __syncthreads.)

        const char* sbase = (const char*)(&sm[k & 1][0]);  // k compile-time under unroll -> ds_read offset imm
        float4* out4 = reinterpret_cast<float4*>(out + (size_t)(b0 + k) * (N_ATOMS * N_ATOMS));
#pragma unroll
        for (int it = 0; it < 4; ++it) {
            const float v0 = *(const float*)(sbase + srcB[it * 4 + 0]);
            const float v1 = *(const float*)(sbase + srcB[it * 4 + 1]);
            const float v2 = *(const float*)(sbase + srcB[it * 4 + 2]);
            const float v3 = *(const float*)(sbase + srcB[it * 4 + 3]);
            out4[it * 256 + t] = make_float4(v0, v1, v2, v3);
        }

        // Trailing barrier: all waves finished reading buffer k&1 before the
        // next iteration's prefetch DMA overwrites it.
        if (k + 1 < ROWS_PER_BLOCK) {
            __builtin_amdgcn_s_barrier();
        }
        rowPtr += NC2;
    }
}

extern "C" void kernel_launch(void* const* d_in, const int* in_sizes, int n_in,
                              void* d_out, int out_size, void* d_ws, size_t ws_size,
                              hipStream_t stream) {
    const float* in = (const float*)d_in[0];
    float* out = (float*)d_out;
    triangle_kernel<<<NBLOCKS, 256, 0, stream>>>(in, out);
}

// Round 3
// 671.347 us; speedup vs baseline: 1.0246x; 1.0246x over previous
//
#include <hip/hip_runtime.h>

constexpr int N_ATOMS = 64;
constexpr int NC2 = N_ATOMS * (N_ATOMS - 1) / 2;  // 2016
constexpr int BATCH = 32768;

// Async global->LDS copy of one 16-byte chunk.
// HW semantics (measured, m104/m108): LDS dest = wave-uniform base + lane*16,
// so every wave's destination pattern MUST be lane-linear from its first lane.
__device__ __forceinline__ void stage_chunk16(const float* g, float* l) {
    __builtin_amdgcn_global_load_lds(
        (const __attribute__((address_space(1))) void*)g,
        (__attribute__((address_space(3))) void*)l, 16, 0, 0);
}

// One block per batch row, 512 threads (8 full waves).
//  - Stage the 2016-float row into LDS via 16B global_load_lds DMA.
//    Waves 0..6: chunks t (0..447). Wave 7: chunks t-8 (440..503) -- chunks
//    440..447 double-staged (same bytes, same address: idempotent). Every
//    wave is full and lane-linear; max LDS write ends at sm[2015].
//  - Each thread then emits 2 coalesced float4 outputs (8 gathered floats).
__global__ __launch_bounds__(512) void triangle_kernel(
    const float* __restrict__ in, float* __restrict__ out) {
    __shared__ __align__(16) float sm[2048];  // 2016 data + zero slot @2016

    const int t = threadIdx.x;
    const int b = blockIdx.x;

    // Zero slot: the "source" for diagonal elements (j == i). Staging never
    // writes past sm[2015], so this survives.
    if (t == 0) sm[2016] = 0.0f;

    const float* row = in + (size_t)b * NC2;
    const int c = (t < 448) ? t : (t - 8);  // wave 7 -> chunks 440..503
    stage_chunk16(row + 4 * c, &sm[4 * c]);

    __syncthreads();  // drains vmcnt (DMA) + lgkmcnt (zero-slot ds_write)

    // --- Emit: 1024 float4 stores, 2 per thread, coalesced per wave ---
    float4* out4 = reinterpret_cast<float4*>(out + (size_t)b * (N_ATOMS * N_ATOMS));
#pragma unroll
    for (int half = 0; half < 2; ++half) {
        const int e4 = half * 512 + t;   // float4 index in [0,1024)
        const int e = e4 * 4;            // element index in [0,4096)
        const int i = e >> 6;            // output row (fixed across the 4 elems)
        const int j0 = e & 63;           // first column
        const int bl = i * (i - 1) / 2;  // start of row i's strict-lower values

        float v[4];
#pragma unroll
        for (int k = 0; k < 4; ++k) {
            const int j = j0 + k;
            int s;
            if (j < i)      s = bl + j;              // lower: contiguous
            else if (j > i) s = j * (j - 1) / 2 + i; // mirrored upper
            else            s = 2016;                // diagonal -> zero slot
            v[k] = sm[s];
        }
        out4[e4] = make_float4(v[0], v[1], v[2], v[3]);
    }
}

extern "C" void kernel_launch(void* const* d_in, const int* in_sizes, int n_in,
                              void* d_out, int out_size, void* d_ws, size_t ws_size,
                              hipStream_t stream) {
    const float* in = (const float*)d_in[0];
    float* out = (float*)d_out;
    triangle_kernel<<<BATCH, 512, 0, stream>>>(in, out);
}